// Round 1
// baseline (931.235 us; speedup 1.0000x reference)
//
#include <hip/hip_runtime.h>
#include <math.h>

#define NSEG 65536
#define FDIM 64
#define CAP  40   // rows cached in LDS per segment: 40*64*4B = 10 KB -> 16 blocks/CU

// ---------------- pass A: per-segment histogram ----------------
__global__ __launch_bounds__(256) void hist_kernel(const int* __restrict__ idx,
                                                   int* __restrict__ counts, int n) {
    int i = blockIdx.x * blockDim.x + threadIdx.x;
    int stride = gridDim.x * blockDim.x;
    for (; i < n; i += stride) {
        unsigned s = (unsigned)idx[i];
        if (s < NSEG) atomicAdd(&counts[s], 1);
    }
}

// ---------------- pass B: exclusive prefix sum over 65536 counts (1 block) ----------------
__global__ __launch_bounds__(1024) void scan_kernel(const int* __restrict__ counts,
                                                    int* __restrict__ offs) {
    __shared__ int part[1024];
    const int tid  = threadIdx.x;
    const int base = tid * 64;
    int s = 0;
    for (int j = 0; j < 64; ++j) s += counts[base + j];
    part[tid] = s;
    __syncthreads();
    // Hillis-Steele inclusive scan over 1024 partials
    for (int off = 1; off < 1024; off <<= 1) {
        int v = (tid >= off) ? part[tid - off] : 0;
        __syncthreads();
        part[tid] += v;
        __syncthreads();
    }
    int run = part[tid] - s;  // exclusive
    for (int j = 0; j < 64; ++j) { offs[base + j] = run; run += counts[base + j]; }
}

// ---------------- pass C: scatter instance ids into segment-sorted order ----------------
__global__ __launch_bounds__(256) void scatter_kernel(const int* __restrict__ idx,
                                                      const int* __restrict__ offs,
                                                      int* __restrict__ cursor,
                                                      int* __restrict__ sorted, int n) {
    int i = blockIdx.x * blockDim.x + threadIdx.x;
    int stride = gridDim.x * blockDim.x;
    for (; i < n; i += stride) {
        unsigned s = (unsigned)idx[i];
        if (s < NSEG) {
            int p = offs[s] + atomicAdd(&cursor[s], 1);
            sorted[p] = i;
        }
    }
}

// ---------------- pass D: one wave per segment; lane = feature ----------------
__global__ __launch_bounds__(64) void seg_main(const float* __restrict__ x,
                                               const int* __restrict__ sorted,
                                               const int* __restrict__ offs,
                                               const int* __restrict__ counts,
                                               const float* __restrict__ t,
                                               const float* __restrict__ W,
                                               float* __restrict__ out) {
    const int s    = blockIdx.x;
    const int lane = threadIdx.x;   // feature index 0..63
    const int beg  = offs[s];
    const int cnt  = counts[s];

    __shared__ float rows[CAP][FDIM];   // stride 64 floats: 2-way bank alias = free

    float mn = INFINITY, mx = -INFINITY, sm = 0.0f;

    // ---- pass 1: min / max / sum, cache first CAP rows in LDS ----
    for (int base = 0; base < cnt; base += 64) {
        const int m = min(64, cnt - base);
        int myidx = (lane < m) ? sorted[beg + base + lane] : 0;
        int r = 0;
        for (; r + 4 <= m; r += 4) {
            int q0 = __shfl(myidx, r);
            int q1 = __shfl(myidx, r + 1);
            int q2 = __shfl(myidx, r + 2);
            int q3 = __shfl(myidx, r + 3);
            float v0 = x[(size_t)q0 * FDIM + lane];
            float v1 = x[(size_t)q1 * FDIM + lane];
            float v2 = x[(size_t)q2 * FDIM + lane];
            float v3 = x[(size_t)q3 * FDIM + lane];
            const int g = base + r;
            if (g + 0 < CAP) rows[g + 0][lane] = v0;
            if (g + 1 < CAP) rows[g + 1][lane] = v1;
            if (g + 2 < CAP) rows[g + 2][lane] = v2;
            if (g + 3 < CAP) rows[g + 3][lane] = v3;
            mn = fminf(mn, fminf(fminf(v0, v1), fminf(v2, v3)));
            mx = fmaxf(mx, fmaxf(fmaxf(v0, v1), fmaxf(v2, v3)));
            sm += v0 + v1 + v2 + v3;
        }
        for (; r < m; ++r) {
            int q = __shfl(myidx, r);
            float v = x[(size_t)q * FDIM + lane];
            const int g = base + r;
            if (g < CAP) rows[g][lane] = v;
            mn = fminf(mn, v);
            mx = fmaxf(mx, v);
            sm += v;
        }
    }
    __syncthreads();

    // ---- pass 2: relu_sum with adaptive bias ----
    const float tc   = fminf(fmaxf(t[lane], 0.0f), 1.0f);
    const float bias = tc * mx + (1.0f - tc) * mn;
    float rs = 0.0f;
    const int lim = min(cnt, CAP);
    for (int r = 0; r < lim; ++r)
        rs += fmaxf(0.0f, rows[r][lane] - bias);
    // overflow rows (rare): reread from global (L2-hot)
    for (int base = CAP; base < cnt; base += 64) {
        const int m = min(64, cnt - base);
        int myidx = (lane < m) ? sorted[beg + base + lane] : 0;
        for (int r = 0; r < m; ++r) {
            int q = __shfl(myidx, r);
            rs += fmaxf(0.0f, x[(size_t)q * FDIM + lane] - bias);
        }
    }

    // ---- epilogue: 5-tap linear combine, coords order [n, min, max, relu_sum, sum] ----
    const float W0 = W[0], W1 = W[1], W2 = W[2], W3 = W[3], W4 = W[4];
    out[(size_t)s * FDIM + lane] =
        W0 * (float)cnt + W1 * mn + W2 * mx + W3 * rs + W4 * sm;
}

extern "C" void kernel_launch(void* const* d_in, const int* in_sizes, int n_in,
                              void* d_out, int out_size, void* d_ws, size_t ws_size,
                              hipStream_t stream) {
    const float* x    = (const float*)d_in[0];
    const int*   bidx = (const int*)d_in[1];   // harness: integer -> const int*
    const float* t    = (const float*)d_in[3];
    const float* W    = (const float*)d_in[4];
    float*       out  = (float*)d_out;
    const int    N    = in_sizes[0] / FDIM;

    // workspace layout: counts | offs | cursor | sorted   (~8.8 MB total)
    int* counts = (int*)d_ws;
    int* offs   = counts + NSEG;
    int* cursor = offs + NSEG;
    int* sorted = cursor + NSEG;

    hipMemsetAsync(counts, 0, NSEG * sizeof(int), stream);
    hipMemsetAsync(cursor, 0, NSEG * sizeof(int), stream);

    hist_kernel<<<2048, 256, 0, stream>>>(bidx, counts, N);
    scan_kernel<<<1, 1024, 0, stream>>>(counts, offs);
    scatter_kernel<<<2048, 256, 0, stream>>>(bidx, offs, cursor, sorted, N);
    seg_main<<<NSEG, 64, 0, stream>>>(x, sorted, offs, counts, t, W, out);
}